// Round 5
// baseline (7114.342 us; speedup 1.0000x reference)
//
#include <hip/hip_runtime.h>
#include <hip/hip_bf16.h>
#include <stdint.h>

typedef float  f32x16 __attribute__((ext_vector_type(16)));
typedef __bf16 bf16x8 __attribute__((ext_vector_type(8)));
typedef unsigned u32x4 __attribute__((ext_vector_type(4)));

#define NH 1280
#define MAT_ELEMS (80 * NH * 16)   // u16 elems per 1280x1280 matrix

// workspace offsets (bytes)
#define OFF_W1S  0u
#define OFF_W2S  6553600u
#define OFF_W3S  9830400u
#define OFF_HI   13107200u
#define OFF_HJB  18350080u
#define OFF_H2   23592960u   // 1024 tiles * 163840 B

__device__ __forceinline__ unsigned short bfb(float f) {
    unsigned u = __builtin_bit_cast(unsigned, f);
    u += 0x7fffu + ((u >> 16) & 1u);          // RNE
    return (unsigned short)(u >> 16);
}
__device__ __forceinline__ unsigned pk2(float lo, float hi) {
    return (unsigned)bfb(lo) | ((unsigned)bfb(hi) << 16);
}

// ---------------------------------------------------------------------------
// k_cvt: f32 row-major -> bf16 MFMA-B fragment-linear (verified).
// ---------------------------------------------------------------------------
__global__ void k_cvt(const float* __restrict__ src, unsigned short* __restrict__ dst) {
    __shared__ float tile[16][257];
    const int kb = blockIdx.x, cb = blockIdx.y, t = threadIdx.x;
#pragma unroll
    for (int r = 0; r < 16; ++r)
        tile[r][t] = src[(size_t)(kb * 16 + r) * NH + cb * 256 + t];
    __syncthreads();
    const int col = cb * 256 + t;
    unsigned u[8];
#pragma unroll
    for (int i = 0; i < 8; ++i) u[i] = pk2(tile[2 * i][t], tile[2 * i + 1][t]);
    u32x4* d = (u32x4*)(dst + ((size_t)kb * NH + col) * 16);
    u32x4 w0 = {u[0], u[1], u[2], u[3]}, w1 = {u[4], u[5], u[6], u[7]};
    d[0] = w0; d[1] = w1;
}

// ---------------------------------------------------------------------------
// Two-tile K-half GEMM: acc[0..1] = tile A rows 0-31/32-63, acc[2..3] = tile B.
// One B-frag stream feeds 20 MFMAs per kblk -> B traffic halved, L2 latency
// covered by ~320 MFMA cycles with only 2-deep prefetch.
// LDS half layout: 64 rows x 640 bf16, rowstride 1280 B, XOR swizzle.
// ---------------------------------------------------------------------------
__device__ __forceinline__ void gemm_half2(const char* aA, const char* aB,
                                           unsigned xr, unsigned h16,
                                           const char* bph, f32x16 acc[4][5]) {
    bf16x8 P0[5], P1[5];
#define LDBH2(D_, KL_) { _Pragma("unroll") for (int cf = 0; cf < 5; ++cf) \
    D_[cf] = __builtin_bit_cast(bf16x8, *(const uint4*)(bph + (size_t)(KL_) * 40960 + cf * 1024)); }
#define MF20(P_, KL_) { unsigned ko = ((unsigned)(KL_) * 32u + h16) ^ xr; \
    bf16x8 a0 = __builtin_bit_cast(bf16x8, *(const uint4*)(aA + ko)); \
    bf16x8 a1 = __builtin_bit_cast(bf16x8, *(const uint4*)(aA + 40960 + ko)); \
    bf16x8 c0 = __builtin_bit_cast(bf16x8, *(const uint4*)(aB + ko)); \
    bf16x8 c1 = __builtin_bit_cast(bf16x8, *(const uint4*)(aB + 40960 + ko)); \
    _Pragma("unroll") for (int cf = 0; cf < 5; ++cf) { \
        acc[0][cf] = __builtin_amdgcn_mfma_f32_32x32x16_bf16(a0, P_[cf], acc[0][cf], 0, 0, 0); \
        acc[1][cf] = __builtin_amdgcn_mfma_f32_32x32x16_bf16(a1, P_[cf], acc[1][cf], 0, 0, 0); \
        acc[2][cf] = __builtin_amdgcn_mfma_f32_32x32x16_bf16(c0, P_[cf], acc[2][cf], 0, 0, 0); \
        acc[3][cf] = __builtin_amdgcn_mfma_f32_32x32x16_bf16(c1, P_[cf], acc[3][cf], 0, 0, 0); } }
    LDBH2(P0, 0) LDBH2(P1, 1)
    for (int kl = 0; kl < 38; kl += 2) {
        MF20(P0, kl)     LDBH2(P0, kl + 2)
        MF20(P1, kl + 1) LDBH2(P1, kl + 3)
    }
    MF20(P0, 38) MF20(P1, 39)
#undef LDBH2
#undef MF20
}

// Single-tile variant (k_hihj only; 32 WGs, not perf-critical).
__device__ __forceinline__ void gemm_half1(const char* aA, unsigned xr, unsigned h16,
                                           const char* bph, f32x16 acc[2][5]) {
    bf16x8 P0[5], P1[5];
#define LDBH1(D_, KL_) { _Pragma("unroll") for (int cf = 0; cf < 5; ++cf) \
    D_[cf] = __builtin_bit_cast(bf16x8, *(const uint4*)(bph + (size_t)(KL_) * 40960 + cf * 1024)); }
#define MF10(P_, KL_) { unsigned ko = ((unsigned)(KL_) * 32u + h16) ^ xr; \
    bf16x8 a0 = __builtin_bit_cast(bf16x8, *(const uint4*)(aA + ko)); \
    bf16x8 a1 = __builtin_bit_cast(bf16x8, *(const uint4*)(aA + 40960 + ko)); \
    _Pragma("unroll") for (int cf = 0; cf < 5; ++cf) { \
        acc[0][cf] = __builtin_amdgcn_mfma_f32_32x32x16_bf16(a0, P_[cf], acc[0][cf], 0, 0, 0); \
        acc[1][cf] = __builtin_amdgcn_mfma_f32_32x32x16_bf16(a1, P_[cf], acc[1][cf], 0, 0, 0); } }
    LDBH1(P0, 0) LDBH1(P1, 1)
    for (int kl = 0; kl < 38; kl += 2) {
        MF10(P0, kl)     LDBH1(P0, kl + 2)
        MF10(P1, kl + 1) LDBH1(P1, kl + 3)
    }
    MF10(P0, 38) MF10(P1, 39)
#undef LDBH1
#undef MF10
}

__device__ __forceinline__ void zero4(f32x16 acc[4][5]) {
#pragma unroll
    for (int r = 0; r < 4; ++r)
#pragma unroll
        for (int c = 0; c < 5; ++c)
#pragma unroll
            for (int i = 0; i < 16; ++i) acc[r][c][i] = 0.f;
}
__device__ __forceinline__ void zero2(f32x16 acc[2][5]) {
#pragma unroll
    for (int r = 0; r < 2; ++r)
#pragma unroll
        for (int c = 0; c < 5; ++c)
#pragma unroll
            for (int i = 0; i < 16; ++i) acc[r][c][i] = 0.f;
}

// ---------------------------------------------------------------------------
// k_hihj: Hi = roi@W1[:C]; Hjb = roi@W1[C:] + b1   (32 WGs; K-half restaged)
// ---------------------------------------------------------------------------
__global__ __launch_bounds__(512, 2) void k_hihj(const float* __restrict__ roi, const float* __restrict__ b1,
                                                 const unsigned short* __restrict__ w1s,
                                                 float* __restrict__ Hi, float* __restrict__ Hjb) {
    __shared__ __align__(16) char lds[81920];
    const int b = blockIdx.x >> 1, hh = blockIdx.x & 1, tid = threadIdx.x;
    const float* src = roi + (size_t)b * 64 * NH;
    const int wave = tid >> 6, lane = tid & 63, rlo = lane & 31, hsel = lane >> 5;
    const int colbase = wave * 160;
    const unsigned xr = (unsigned)(rlo & 7) << 4, h16 = (unsigned)hsel * 16u;
    const char* aA = lds + rlo * 1280;
    const char* bp = (const char*)(w1s + (size_t)hh * MAT_ELEMS) + (size_t)(colbase + rlo) * 32 + (size_t)hsel * 16;
    f32x16 acc[2][5]; zero2(acc);
    for (int kh = 0; kh < 2; ++kh) {
        if (kh) __syncthreads();
        for (int q = 0; q < 10; ++q) {
            int cid = tid + (q << 9);
            int row = cid / 80, c8 = (cid - row * 80) << 3, col = kh * 640 + c8;
            const float* r = src + row * NH + col;
            float4 v0 = *(const float4*)r, v1 = *(const float4*)(r + 4);
            uint4 pk;
            pk.x = pk2(v0.x, v0.y); pk.y = pk2(v0.z, v0.w);
            pk.z = pk2(v1.x, v1.y); pk.w = pk2(v1.z, v1.w);
            *(uint4*)(lds + row * 1280 + (((unsigned)(c8 << 1)) ^ ((unsigned)(row & 7) << 4))) = pk;
        }
        __syncthreads();
        gemm_half1(aA, xr, h16, bp + (size_t)kh * 40 * 40960, acc);
    }
    float bias[5];
#pragma unroll
    for (int cf = 0; cf < 5; ++cf) bias[cf] = hh ? b1[colbase + cf * 32 + rlo] : 0.f;
    float* dst = hh ? Hjb : Hi;
#pragma unroll
    for (int rf = 0; rf < 2; ++rf)
#pragma unroll
        for (int cf = 0; cf < 5; ++cf) {
            int col = colbase + cf * 32 + rlo;
#pragma unroll
            for (int j = 0; j < 16; ++j) {
                int row = rf * 32 + (j & 3) + ((j >> 2) << 3) + (hsel << 2);
                dst[(size_t)(b * 64 + row) * NH + col] = acc[rf][cf][j] + bias[cf];
            }
        }
}

// ---------------------------------------------------------------------------
// k_g1: WG = (b, n-pair). h1 tiles for n0,n1 staged per K-half (Hi rows read
// once, shared). h2 = relu(h1@W2+b2) -> two 160KB images -> NT store.
// ---------------------------------------------------------------------------
__global__ __launch_bounds__(512, 2) void k_g1(const float* __restrict__ Hi, const float* __restrict__ Hjb,
                                               const float* __restrict__ b2,
                                               const unsigned short* __restrict__ w2s,
                                               char* __restrict__ h2g) {
    __shared__ __align__(16) char lds[163840];
    char* bufA = lds; char* bufB = lds + 81920;
    const int wg = blockIdx.x, b = wg >> 5, np = wg & 31;
    const int g0 = b * 64 + np * 2;
    const int tid = threadIdx.x;
    const float* HiB = Hi + (size_t)b * 64 * NH;
    const float* Hj0 = Hjb + (size_t)g0 * NH;
    const float* Hj1 = Hj0 + NH;
    const int wave = tid >> 6, lane = tid & 63, rlo = lane & 31, hsel = lane >> 5;
    const int colbase = wave * 160;
    const unsigned xr = (unsigned)(rlo & 7) << 4, h16 = (unsigned)hsel * 16u;
    const char* aA = bufA + rlo * 1280;
    const char* aB = bufB + rlo * 1280;
    const char* bp = (const char*)w2s + (size_t)(colbase + rlo) * 32 + (size_t)hsel * 16;
    f32x16 acc[4][5]; zero4(acc);
    for (int kh = 0; kh < 2; ++kh) {
        if (kh) __syncthreads();
        for (int q = 0; q < 10; ++q) {
            int cid = tid + (q << 9);
            int row = cid / 80, c8 = (cid - row * 80) << 3, col = kh * 640 + c8;
            const float* r = HiB + row * NH + col;
            float4 h0 = *(const float4*)r, h1 = *(const float4*)(r + 4);
            float4 p0 = *(const float4*)(Hj0 + col), p1 = *(const float4*)(Hj0 + col + 4);
            float4 q0 = *(const float4*)(Hj1 + col), q1 = *(const float4*)(Hj1 + col + 4);
            unsigned off = row * 1280 + (((unsigned)(c8 << 1)) ^ ((unsigned)(row & 7) << 4));
            uint4 pkA, pkB;
            pkA.x = pk2(fmaxf(h0.x + p0.x, 0.f), fmaxf(h0.y + p0.y, 0.f));
            pkA.y = pk2(fmaxf(h0.z + p0.z, 0.f), fmaxf(h0.w + p0.w, 0.f));
            pkA.z = pk2(fmaxf(h1.x + p1.x, 0.f), fmaxf(h1.y + p1.y, 0.f));
            pkA.w = pk2(fmaxf(h1.z + p1.z, 0.f), fmaxf(h1.w + p1.w, 0.f));
            pkB.x = pk2(fmaxf(h0.x + q0.x, 0.f), fmaxf(h0.y + q0.y, 0.f));
            pkB.y = pk2(fmaxf(h0.z + q0.z, 0.f), fmaxf(h0.w + q0.w, 0.f));
            pkB.z = pk2(fmaxf(h1.x + q1.x, 0.f), fmaxf(h1.y + q1.y, 0.f));
            pkB.w = pk2(fmaxf(h1.z + q1.z, 0.f), fmaxf(h1.w + q1.w, 0.f));
            *(uint4*)(bufA + off) = pkA;
            *(uint4*)(bufB + off) = pkB;
        }
        __syncthreads();
        gemm_half2(aA, aB, xr, h16, bp + (size_t)kh * 40 * 40960, acc);
    }
    float bv[5];
#pragma unroll
    for (int cf = 0; cf < 5; ++cf) bv[cf] = b2[colbase + cf * 32 + rlo];
    char* ibuf = (wave < 4) ? bufA : bufB;
    const int cb2 = (wave < 4) ? colbase : colbase - 640;
#pragma unroll
    for (int t = 0; t < 2; ++t) {
        __syncthreads();                   // prior LDS reads (gemm / dump t-1) done
#pragma unroll
        for (int rf = 0; rf < 2; ++rf)
#pragma unroll
            for (int cf = 0; cf < 5; ++cf) {
                int cl = cb2 + cf * 32 + rlo;
#pragma unroll
                for (int j = 0; j < 16; ++j) {
                    int row = rf * 32 + (j & 3) + ((j >> 2) << 3) + (hsel << 2);
                    float v = fmaxf(acc[t * 2 + rf][cf][j] + bv[cf], 0.f);
                    *(unsigned short*)(ibuf + row * 1280 +
                        (((unsigned)(cl << 1)) ^ ((unsigned)(row & 7) << 4))) = bfb(v);
                }
            }
        __syncthreads();                   // image complete
        u32x4* dst = (u32x4*)(h2g + (size_t)(g0 + t) * 163840);
        const u32x4* ls = (const u32x4*)lds;
        for (int q = 0; q < 20; ++q) {
            int idx = tid + (q << 9);
            __builtin_nontemporal_store(ls[idx], dst + idx);
        }
    }
}

// ---------------------------------------------------------------------------
// k_g2: WG = (b, n-pair). Stage both tiles' h2 K-half images (NT), GEMM vs
// W3, relu+row-reduce, atomicAdd.
// ---------------------------------------------------------------------------
__global__ __launch_bounds__(512, 2) void k_g2(const char* __restrict__ h2g,
                                               const float* __restrict__ b3,
                                               const unsigned short* __restrict__ w3s,
                                               float* __restrict__ out) {
    __shared__ __align__(16) char lds[163840];
    char* bufA = lds; char* bufB = lds + 81920;
    const int wg = blockIdx.x, b = wg >> 5, np = wg & 31;
    const int g0 = b * 64 + np * 2;
    const int tid = threadIdx.x;
    const int wave = tid >> 6, lane = tid & 63, rlo = lane & 31, hsel = lane >> 5;
    const int colbase = wave * 160;
    const unsigned xr = (unsigned)(rlo & 7) << 4, h16 = (unsigned)hsel * 16u;
    const char* aA = bufA + rlo * 1280;
    const char* aB = bufB + rlo * 1280;
    const char* bp = (const char*)w3s + (size_t)(colbase + rlo) * 32 + (size_t)hsel * 16;
    f32x16 acc[4][5]; zero4(acc);
    for (int kh = 0; kh < 2; ++kh) {
        if (kh) __syncthreads();
        const u32x4* s0 = (const u32x4*)(h2g + (size_t)g0 * 163840 + (size_t)kh * 81920);
        const u32x4* s1 = (const u32x4*)(h2g + (size_t)(g0 + 1) * 163840 + (size_t)kh * 81920);
        for (int q = 0; q < 10; ++q) {
            int idx = tid + (q << 9);
            u32x4 va = __builtin_nontemporal_load(s0 + idx);
            u32x4 vb = __builtin_nontemporal_load(s1 + idx);
            *(u32x4*)(bufA + ((size_t)idx << 4)) = va;
            *(u32x4*)(bufB + ((size_t)idx << 4)) = vb;
        }
        __syncthreads();
        gemm_half2(aA, aB, xr, h16, bp + (size_t)kh * 40 * 40960, acc);
    }
    float b3v[5];
#pragma unroll
    for (int cf = 0; cf < 5; ++cf) b3v[cf] = b3[colbase + cf * 32 + rlo];
#pragma unroll
    for (int t = 0; t < 2; ++t)
#pragma unroll
        for (int cf = 0; cf < 5; ++cf) {
            float sum = 0.f;
#pragma unroll
            for (int rf = 0; rf < 2; ++rf)
#pragma unroll
                for (int j = 0; j < 16; ++j) sum += fmaxf(acc[t * 2 + rf][cf][j] + b3v[cf], 0.f);
            sum += __shfl_xor(sum, 32);    // other 32 rows live on lane ^ 32
            if (lane < 32) atomicAdd(out + b * NH + colbase + cf * 32 + lane, sum);
        }
}

extern "C" void kernel_launch(void* const* d_in, const int* in_sizes, int n_in,
                              void* d_out, int out_size, void* d_ws, size_t ws_size,
                              hipStream_t stream) {
    const float* roi = (const float*)d_in[0];
    const float* W1  = (const float*)d_in[1];
    const float* b1  = (const float*)d_in[2];
    const float* W2  = (const float*)d_in[3];
    const float* b2  = (const float*)d_in[4];
    const float* W3  = (const float*)d_in[5];
    const float* b3  = (const float*)d_in[6];
    float* out = (float*)d_out;
    char* ws = (char*)d_ws;
    unsigned short* w1s = (unsigned short*)(ws + OFF_W1S);
    unsigned short* w2s = (unsigned short*)(ws + OFF_W2S);
    unsigned short* w3s = (unsigned short*)(ws + OFF_W3S);
    float* Hi  = (float*)(ws + OFF_HI);
    float* Hjb = (float*)(ws + OFF_HJB);
    char*  h2g = ws + OFF_H2;

    (void)hipMemsetAsync(out, 0, (size_t)16 * NH * sizeof(float), stream);

    k_cvt<<<dim3(80, 5), 256, 0, stream>>>(W1, w1s);
    k_cvt<<<dim3(80, 5), 256, 0, stream>>>(W1 + (size_t)NH * NH, w1s + MAT_ELEMS);
    k_cvt<<<dim3(80, 5), 256, 0, stream>>>(W2, w2s);
    k_cvt<<<dim3(80, 5), 256, 0, stream>>>(W3, w3s);

    k_hihj<<<32, 512, 0, stream>>>(roi, b1, w1s, Hi, Hjb);
    k_g1<<<512, 512, 0, stream>>>(Hi, Hjb, b2, w2s, h2g);
    k_g2<<<512, 512, 0, stream>>>(h2g, b3, w3s, out);
}

// Round 6
// 7113.733 us; speedup vs baseline: 1.0001x; 1.0001x over previous
//
#include <hip/hip_runtime.h>
#include <hip/hip_bf16.h>
#include <stdint.h>

typedef float  f32x16 __attribute__((ext_vector_type(16)));
typedef __bf16 bf16x8 __attribute__((ext_vector_type(8)));
typedef unsigned u32x4 __attribute__((ext_vector_type(4)));

#define NH 1280
#define MAT_ELEMS (80 * NH * 16)   // u16 elems per 1280x1280 matrix

// workspace offsets (bytes)
#define OFF_W1S  0u
#define OFF_W2S  6553600u
#define OFF_W3S  9830400u
#define OFF_HI   13107200u
#define OFF_HJB  18350080u
#define OFF_H2   23592960u   // 1024 tiles * 163840 B

__device__ __forceinline__ unsigned short bfb(float f) {
    unsigned u = __builtin_bit_cast(unsigned, f);
    u += 0x7fffu + ((u >> 16) & 1u);          // RNE
    return (unsigned short)(u >> 16);
}
__device__ __forceinline__ unsigned pk2(float lo, float hi) {
    return (unsigned)bfb(lo) | ((unsigned)bfb(hi) << 16);
}

// ---------------------------------------------------------------------------
// k_cvt: f32 row-major -> bf16 MFMA-B fragment-linear (verified).
// ---------------------------------------------------------------------------
__global__ void k_cvt(const float* __restrict__ src, unsigned short* __restrict__ dst) {
    __shared__ float tile[16][257];
    const int kb = blockIdx.x, cb = blockIdx.y, t = threadIdx.x;
#pragma unroll
    for (int r = 0; r < 16; ++r)
        tile[r][t] = src[(size_t)(kb * 16 + r) * NH + cb * 256 + t];
    __syncthreads();
    const int col = cb * 256 + t;
    unsigned u[8];
#pragma unroll
    for (int i = 0; i < 8; ++i) u[i] = pk2(tile[2 * i][t], tile[2 * i + 1][t]);
    u32x4* d = (u32x4*)(dst + ((size_t)kb * NH + col) * 16);
    u32x4 w0 = {u[0], u[1], u[2], u[3]}, w1 = {u[4], u[5], u[6], u[7]};
    d[0] = w0; d[1] = w1;
}

// ---------------------------------------------------------------------------
// Two-tile K-half GEMM: acc[0..1] = tile A rows 0-31/32-63, acc[2..3] = tile B.
// One B-frag stream feeds 20 MFMAs per kblk -> B traffic halved, L2 latency
// covered by ~320 MFMA cycles with 2-deep prefetch.
// LDS half layout: 64 rows x 640 bf16, rowstride 1280 B, XOR swizzle.
// ---------------------------------------------------------------------------
__device__ __forceinline__ void gemm_half2(const char* aA, const char* aB,
                                           unsigned xr, unsigned h16,
                                           const char* bph, f32x16 acc[4][5]) {
    bf16x8 P0[5], P1[5];
#define LDBH2(D_, KL_) { _Pragma("unroll") for (int cf = 0; cf < 5; ++cf) \
    D_[cf] = __builtin_bit_cast(bf16x8, *(const uint4*)(bph + (size_t)(KL_) * 40960 + cf * 1024)); }
#define MF20(P_, KL_) { unsigned ko = ((unsigned)(KL_) * 32u + h16) ^ xr; \
    bf16x8 a0 = __builtin_bit_cast(bf16x8, *(const uint4*)(aA + ko)); \
    bf16x8 a1 = __builtin_bit_cast(bf16x8, *(const uint4*)(aA + 40960 + ko)); \
    bf16x8 c0 = __builtin_bit_cast(bf16x8, *(const uint4*)(aB + ko)); \
    bf16x8 c1 = __builtin_bit_cast(bf16x8, *(const uint4*)(aB + 40960 + ko)); \
    _Pragma("unroll") for (int cf = 0; cf < 5; ++cf) { \
        acc[0][cf] = __builtin_amdgcn_mfma_f32_32x32x16_bf16(a0, P_[cf], acc[0][cf], 0, 0, 0); \
        acc[1][cf] = __builtin_amdgcn_mfma_f32_32x32x16_bf16(a1, P_[cf], acc[1][cf], 0, 0, 0); \
        acc[2][cf] = __builtin_amdgcn_mfma_f32_32x32x16_bf16(c0, P_[cf], acc[2][cf], 0, 0, 0); \
        acc[3][cf] = __builtin_amdgcn_mfma_f32_32x32x16_bf16(c1, P_[cf], acc[3][cf], 0, 0, 0); } }
    LDBH2(P0, 0) LDBH2(P1, 1)
    for (int kl = 0; kl < 38; kl += 2) {
        MF20(P0, kl)     LDBH2(P0, kl + 2)
        MF20(P1, kl + 1) LDBH2(P1, kl + 3)
    }
    MF20(P0, 38) MF20(P1, 39)
#undef LDBH2
#undef MF20
}

// Single-tile variant (k_hihj only; 32 WGs, not perf-critical).
__device__ __forceinline__ void gemm_half1(const char* aA, unsigned xr, unsigned h16,
                                           const char* bph, f32x16 acc[2][5]) {
    bf16x8 P0[5], P1[5];
#define LDBH1(D_, KL_) { _Pragma("unroll") for (int cf = 0; cf < 5; ++cf) \
    D_[cf] = __builtin_bit_cast(bf16x8, *(const uint4*)(bph + (size_t)(KL_) * 40960 + cf * 1024)); }
#define MF10(P_, KL_) { unsigned ko = ((unsigned)(KL_) * 32u + h16) ^ xr; \
    bf16x8 a0 = __builtin_bit_cast(bf16x8, *(const uint4*)(aA + ko)); \
    bf16x8 a1 = __builtin_bit_cast(bf16x8, *(const uint4*)(aA + 40960 + ko)); \
    _Pragma("unroll") for (int cf = 0; cf < 5; ++cf) { \
        acc[0][cf] = __builtin_amdgcn_mfma_f32_32x32x16_bf16(a0, P_[cf], acc[0][cf], 0, 0, 0); \
        acc[1][cf] = __builtin_amdgcn_mfma_f32_32x32x16_bf16(a1, P_[cf], acc[1][cf], 0, 0, 0); } }
    LDBH1(P0, 0) LDBH1(P1, 1)
    for (int kl = 0; kl < 38; kl += 2) {
        MF10(P0, kl)     LDBH1(P0, kl + 2)
        MF10(P1, kl + 1) LDBH1(P1, kl + 3)
    }
    MF10(P0, 38) MF10(P1, 39)
#undef LDBH1
#undef MF10
}

__device__ __forceinline__ void zero4(f32x16 acc[4][5]) {
#pragma unroll
    for (int r = 0; r < 4; ++r)
#pragma unroll
        for (int c = 0; c < 5; ++c)
#pragma unroll
            for (int i = 0; i < 16; ++i) acc[r][c][i] = 0.f;
}
__device__ __forceinline__ void zero2(f32x16 acc[2][5]) {
#pragma unroll
    for (int r = 0; r < 2; ++r)
#pragma unroll
        for (int c = 0; c < 5; ++c)
#pragma unroll
            for (int i = 0; i < 16; ++i) acc[r][c][i] = 0.f;
}

// ---------------------------------------------------------------------------
// k_hihj: Hi = roi@W1[:C]; Hjb = roi@W1[C:] + b1   (32 WGs; K-half restaged)
// ---------------------------------------------------------------------------
__global__ __launch_bounds__(512, 2) void k_hihj(const float* __restrict__ roi, const float* __restrict__ b1,
                                                 const unsigned short* __restrict__ w1s,
                                                 float* __restrict__ Hi, float* __restrict__ Hjb) {
    __shared__ __align__(16) char lds[81920];
    const int b = blockIdx.x >> 1, hh = blockIdx.x & 1, tid = threadIdx.x;
    const float* src = roi + (size_t)b * 64 * NH;
    const int wave = tid >> 6, lane = tid & 63, rlo = lane & 31, hsel = lane >> 5;
    const int colbase = wave * 160;
    const unsigned xr = (unsigned)(rlo & 7) << 4, h16 = (unsigned)hsel * 16u;
    const char* aA = lds + rlo * 1280;
    const char* bp = (const char*)(w1s + (size_t)hh * MAT_ELEMS) + (size_t)(colbase + rlo) * 32 + (size_t)hsel * 16;
    f32x16 acc[2][5]; zero2(acc);
    for (int kh = 0; kh < 2; ++kh) {
        if (kh) __syncthreads();
        for (int q = 0; q < 10; ++q) {
            int cid = tid + (q << 9);
            int row = cid / 80, c8 = (cid - row * 80) << 3, col = kh * 640 + c8;
            const float* r = src + row * NH + col;
            float4 v0 = *(const float4*)r, v1 = *(const float4*)(r + 4);
            uint4 pk;
            pk.x = pk2(v0.x, v0.y); pk.y = pk2(v0.z, v0.w);
            pk.z = pk2(v1.x, v1.y); pk.w = pk2(v1.z, v1.w);
            *(uint4*)(lds + row * 1280 + (((unsigned)(c8 << 1)) ^ ((unsigned)(row & 7) << 4))) = pk;
        }
        __syncthreads();
        gemm_half1(aA, xr, h16, bp + (size_t)kh * 40 * 40960, acc);
    }
    float bias[5];
#pragma unroll
    for (int cf = 0; cf < 5; ++cf) bias[cf] = hh ? b1[colbase + cf * 32 + rlo] : 0.f;
    float* dst = hh ? Hjb : Hi;
#pragma unroll
    for (int rf = 0; rf < 2; ++rf)
#pragma unroll
        for (int cf = 0; cf < 5; ++cf) {
            int col = colbase + cf * 32 + rlo;
#pragma unroll
            for (int j = 0; j < 16; ++j) {
                int row = rf * 32 + (j & 3) + ((j >> 2) << 3) + (hsel << 2);
                dst[(size_t)(b * 64 + row) * NH + col] = acc[rf][cf][j] + bias[cf];
            }
        }
}

// ---------------------------------------------------------------------------
// k_g1: WG = (b, n-pair). h1 tiles for n0,n1 staged per K-half (Hi rows read
// once, shared). h2 = relu(h1@W2+b2) -> two 160KB images -> NT store.
// __launch_bounds__(512,1): acc[4][5]=320 regs needs the full 512-reg budget
// (R5's (512,2) capped at 256 -> 19GB scratch spill, 13x regression).
// ---------------------------------------------------------------------------
__global__ __launch_bounds__(512, 1) void k_g1(const float* __restrict__ Hi, const float* __restrict__ Hjb,
                                               const float* __restrict__ b2,
                                               const unsigned short* __restrict__ w2s,
                                               char* __restrict__ h2g) {
    __shared__ __align__(16) char lds[163840];
    char* bufA = lds; char* bufB = lds + 81920;
    const int wg = blockIdx.x, b = wg >> 5, np = wg & 31;
    const int g0 = b * 64 + np * 2;
    const int tid = threadIdx.x;
    const float* HiB = Hi + (size_t)b * 64 * NH;
    const float* Hj0 = Hjb + (size_t)g0 * NH;
    const float* Hj1 = Hj0 + NH;
    const int wave = tid >> 6, lane = tid & 63, rlo = lane & 31, hsel = lane >> 5;
    const int colbase = wave * 160;
    const unsigned xr = (unsigned)(rlo & 7) << 4, h16 = (unsigned)hsel * 16u;
    const char* aA = bufA + rlo * 1280;
    const char* aB = bufB + rlo * 1280;
    const char* bp = (const char*)w2s + (size_t)(colbase + rlo) * 32 + (size_t)hsel * 16;
    f32x16 acc[4][5]; zero4(acc);
    for (int kh = 0; kh < 2; ++kh) {
        if (kh) __syncthreads();
        for (int q = 0; q < 10; ++q) {
            int cid = tid + (q << 9);
            int row = cid / 80, c8 = (cid - row * 80) << 3, col = kh * 640 + c8;
            const float* r = HiB + row * NH + col;
            float4 h0 = *(const float4*)r, h1 = *(const float4*)(r + 4);
            float4 p0 = *(const float4*)(Hj0 + col), p1 = *(const float4*)(Hj0 + col + 4);
            float4 q0 = *(const float4*)(Hj1 + col), q1 = *(const float4*)(Hj1 + col + 4);
            unsigned off = row * 1280 + (((unsigned)(c8 << 1)) ^ ((unsigned)(row & 7) << 4));
            uint4 pkA, pkB;
            pkA.x = pk2(fmaxf(h0.x + p0.x, 0.f), fmaxf(h0.y + p0.y, 0.f));
            pkA.y = pk2(fmaxf(h0.z + p0.z, 0.f), fmaxf(h0.w + p0.w, 0.f));
            pkA.z = pk2(fmaxf(h1.x + p1.x, 0.f), fmaxf(h1.y + p1.y, 0.f));
            pkA.w = pk2(fmaxf(h1.z + p1.z, 0.f), fmaxf(h1.w + p1.w, 0.f));
            pkB.x = pk2(fmaxf(h0.x + q0.x, 0.f), fmaxf(h0.y + q0.y, 0.f));
            pkB.y = pk2(fmaxf(h0.z + q0.z, 0.f), fmaxf(h0.w + q0.w, 0.f));
            pkB.z = pk2(fmaxf(h1.x + q1.x, 0.f), fmaxf(h1.y + q1.y, 0.f));
            pkB.w = pk2(fmaxf(h1.z + q1.z, 0.f), fmaxf(h1.w + q1.w, 0.f));
            *(uint4*)(bufA + off) = pkA;
            *(uint4*)(bufB + off) = pkB;
        }
        __syncthreads();
        gemm_half2(aA, aB, xr, h16, bp + (size_t)kh * 40 * 40960, acc);
    }
    float bv[5];
#pragma unroll
    for (int cf = 0; cf < 5; ++cf) bv[cf] = b2[colbase + cf * 32 + rlo];
    char* ibuf = (wave < 4) ? bufA : bufB;
    const int cb2 = (wave < 4) ? colbase : colbase - 640;
#pragma unroll
    for (int t = 0; t < 2; ++t) {
        __syncthreads();                   // prior LDS reads (gemm / dump t-1) done
#pragma unroll
        for (int rf = 0; rf < 2; ++rf)
#pragma unroll
            for (int cf = 0; cf < 5; ++cf) {
                int cl = cb2 + cf * 32 + rlo;
#pragma unroll
                for (int j = 0; j < 16; ++j) {
                    int row = rf * 32 + (j & 3) + ((j >> 2) << 3) + (hsel << 2);
                    float v = fmaxf(acc[t * 2 + rf][cf][j] + bv[cf], 0.f);
                    *(unsigned short*)(ibuf + row * 1280 +
                        (((unsigned)(cl << 1)) ^ ((unsigned)(row & 7) << 4))) = bfb(v);
                }
            }
        __syncthreads();                   // image complete
        u32x4* dst = (u32x4*)(h2g + (size_t)(g0 + t) * 163840);
        const u32x4* ls = (const u32x4*)lds;
        for (int q = 0; q < 20; ++q) {
            int idx = tid + (q << 9);
            __builtin_nontemporal_store(ls[idx], dst + idx);
        }
    }
}

// ---------------------------------------------------------------------------
// k_g2: WG = (b, n-pair). Stage both tiles' h2 K-half images (NT), GEMM vs
// W3, relu+row-reduce, atomicAdd.  (512,1): same spill fix as k_g1.
// ---------------------------------------------------------------------------
__global__ __launch_bounds__(512, 1) void k_g2(const char* __restrict__ h2g,
                                               const float* __restrict__ b3,
                                               const unsigned short* __restrict__ w3s,
                                               float* __restrict__ out) {
    __shared__ __align__(16) char lds[163840];
    char* bufA = lds; char* bufB = lds + 81920;
    const int wg = blockIdx.x, b = wg >> 5, np = wg & 31;
    const int g0 = b * 64 + np * 2;
    const int tid = threadIdx.x;
    const int wave = tid >> 6, lane = tid & 63, rlo = lane & 31, hsel = lane >> 5;
    const int colbase = wave * 160;
    const unsigned xr = (unsigned)(rlo & 7) << 4, h16 = (unsigned)hsel * 16u;
    const char* aA = bufA + rlo * 1280;
    const char* aB = bufB + rlo * 1280;
    const char* bp = (const char*)w3s + (size_t)(colbase + rlo) * 32 + (size_t)hsel * 16;
    f32x16 acc[4][5]; zero4(acc);
    for (int kh = 0; kh < 2; ++kh) {
        if (kh) __syncthreads();
        const u32x4* s0 = (const u32x4*)(h2g + (size_t)g0 * 163840 + (size_t)kh * 81920);
        const u32x4* s1 = (const u32x4*)(h2g + (size_t)(g0 + 1) * 163840 + (size_t)kh * 81920);
        for (int q = 0; q < 10; ++q) {
            int idx = tid + (q << 9);
            u32x4 va = __builtin_nontemporal_load(s0 + idx);
            u32x4 vb = __builtin_nontemporal_load(s1 + idx);
            *(u32x4*)(bufA + ((size_t)idx << 4)) = va;
            *(u32x4*)(bufB + ((size_t)idx << 4)) = vb;
        }
        __syncthreads();
        gemm_half2(aA, aB, xr, h16, bp + (size_t)kh * 40 * 40960, acc);
    }
    float b3v[5];
#pragma unroll
    for (int cf = 0; cf < 5; ++cf) b3v[cf] = b3[colbase + cf * 32 + rlo];
#pragma unroll
    for (int t = 0; t < 2; ++t)
#pragma unroll
        for (int cf = 0; cf < 5; ++cf) {
            float sum = 0.f;
#pragma unroll
            for (int rf = 0; rf < 2; ++rf)
#pragma unroll
                for (int j = 0; j < 16; ++j) sum += fmaxf(acc[t * 2 + rf][cf][j] + b3v[cf], 0.f);
            sum += __shfl_xor(sum, 32);    // other 32 rows live on lane ^ 32
            if (lane < 32) atomicAdd(out + b * NH + colbase + cf * 32 + lane, sum);
        }
}

extern "C" void kernel_launch(void* const* d_in, const int* in_sizes, int n_in,
                              void* d_out, int out_size, void* d_ws, size_t ws_size,
                              hipStream_t stream) {
    const float* roi = (const float*)d_in[0];
    const float* W1  = (const float*)d_in[1];
    const float* b1  = (const float*)d_in[2];
    const float* W2  = (const float*)d_in[3];
    const float* b2  = (const float*)d_in[4];
    const float* W3  = (const float*)d_in[5];
    const float* b3  = (const float*)d_in[6];
    float* out = (float*)d_out;
    char* ws = (char*)d_ws;
    unsigned short* w1s = (unsigned short*)(ws + OFF_W1S);
    unsigned short* w2s = (unsigned short*)(ws + OFF_W2S);
    unsigned short* w3s = (unsigned short*)(ws + OFF_W3S);
    float* Hi  = (float*)(ws + OFF_HI);
    float* Hjb = (float*)(ws + OFF_HJB);
    char*  h2g = ws + OFF_H2;

    (void)hipMemsetAsync(out, 0, (size_t)16 * NH * sizeof(float), stream);

    k_cvt<<<dim3(80, 5), 256, 0, stream>>>(W1, w1s);
    k_cvt<<<dim3(80, 5), 256, 0, stream>>>(W1 + (size_t)NH * NH, w1s + MAT_ELEMS);
    k_cvt<<<dim3(80, 5), 256, 0, stream>>>(W2, w2s);
    k_cvt<<<dim3(80, 5), 256, 0, stream>>>(W3, w3s);

    k_hihj<<<32, 512, 0, stream>>>(roi, b1, w1s, Hi, Hjb);
    k_g1<<<512, 512, 0, stream>>>(Hi, Hjb, b2, w2s, h2g);
    k_g2<<<512, 512, 0, stream>>>(h2g, b3, w3s, out);
}

// Round 7
// 483.579 us; speedup vs baseline: 14.7118x; 14.7106x over previous
//
#include <hip/hip_runtime.h>
#include <hip/hip_bf16.h>
#include <stdint.h>

typedef float  f32x16 __attribute__((ext_vector_type(16)));
typedef __bf16 bf16x8 __attribute__((ext_vector_type(8)));
typedef unsigned u32x4 __attribute__((ext_vector_type(4)));

#define NH 1280
#define MAT_ELEMS (80 * NH * 16)   // u16 elems per 1280x1280 matrix

// workspace offsets (bytes)
#define OFF_W1S  0u
#define OFF_W2S  6553600u
#define OFF_W3S  9830400u
#define OFF_HIB  13107200u   // 1024x1280 bf16
#define OFF_HJB  15728640u   // 1024x1280 bf16 (hj + b1)
#define OFF_H2   18350080u   // 2560 blocks * 65536 B (swizzled h2 images)

__device__ __forceinline__ unsigned short bfb(float f) {
    unsigned u = __builtin_bit_cast(unsigned, f);
    u += 0x7fffu + ((u >> 16) & 1u);          // RNE
    return (unsigned short)(u >> 16);
}
__device__ __forceinline__ unsigned pk2(float lo, float hi) {
    return (unsigned)bfb(lo) | ((unsigned)bfb(hi) << 16);
}
// relu(bf16(h)+bf16(j)) for 2 packed bf16 lanes -> packed bf16 (HW RNE via cvt_pk)
__device__ __forceinline__ unsigned relu_add_pk(unsigned h, unsigned j) {
    float h0 = __builtin_bit_cast(float, h << 16);
    float h1 = __builtin_bit_cast(float, h & 0xffff0000u);
    float j0 = __builtin_bit_cast(float, j << 16);
    float j1 = __builtin_bit_cast(float, j & 0xffff0000u);
    float s0 = fmaxf(h0 + j0, 0.f);
    float s1 = fmaxf(h1 + j1, 0.f);
    unsigned d;
    asm("v_cvt_pk_bf16_f32 %0, %1, %2" : "=v"(d) : "v"(s0), "v"(s1));
    return d;
}

// ---------------------------------------------------------------------------
// k_cvt: f32 row-major -> bf16 MFMA-B fragment-linear (verified).
// ---------------------------------------------------------------------------
__global__ void k_cvt(const float* __restrict__ src, unsigned short* __restrict__ dst) {
    __shared__ float tile[16][257];
    const int kb = blockIdx.x, cb = blockIdx.y, t = threadIdx.x;
#pragma unroll
    for (int r = 0; r < 16; ++r)
        tile[r][t] = src[(size_t)(kb * 16 + r) * NH + cb * 256 + t];
    __syncthreads();
    const int col = cb * 256 + t;
    unsigned u[8];
#pragma unroll
    for (int i = 0; i < 8; ++i) u[i] = pk2(tile[2 * i][t], tile[2 * i + 1][t]);
    u32x4* d = (u32x4*)(dst + ((size_t)kb * NH + col) * 16);
    u32x4 w0 = {u[0], u[1], u[2], u[3]}, w1 = {u[4], u[5], u[6], u[7]};
    d[0] = w0; d[1] = w1;
}

// ---------------------------------------------------------------------------
// k_hihj: Hi = roi@W1[:C]; Hjb = roi@W1[C:] + b1, outputs bf16 row-major.
// (32 WGs; inherited verified structure, epilogue now bf16.)
// ---------------------------------------------------------------------------
__device__ __forceinline__ void gemm_half1(const char* aA, unsigned xr, unsigned h16,
                                           const char* bph, f32x16 acc[2][5]) {
    bf16x8 P0[5], P1[5];
#define LDBH1(D_, KL_) { _Pragma("unroll") for (int cf = 0; cf < 5; ++cf) \
    D_[cf] = __builtin_bit_cast(bf16x8, *(const uint4*)(bph + (size_t)(KL_) * 40960 + cf * 1024)); }
#define MF10(P_, KL_) { unsigned ko = ((unsigned)(KL_) * 32u + h16) ^ xr; \
    bf16x8 a0 = __builtin_bit_cast(bf16x8, *(const uint4*)(aA + ko)); \
    bf16x8 a1 = __builtin_bit_cast(bf16x8, *(const uint4*)(aA + 40960 + ko)); \
    _Pragma("unroll") for (int cf = 0; cf < 5; ++cf) { \
        acc[0][cf] = __builtin_amdgcn_mfma_f32_32x32x16_bf16(a0, P_[cf], acc[0][cf], 0, 0, 0); \
        acc[1][cf] = __builtin_amdgcn_mfma_f32_32x32x16_bf16(a1, P_[cf], acc[1][cf], 0, 0, 0); } }
    LDBH1(P0, 0) LDBH1(P1, 1)
    for (int kl = 0; kl < 38; kl += 2) {
        MF10(P0, kl)     LDBH1(P0, kl + 2)
        MF10(P1, kl + 1) LDBH1(P1, kl + 3)
    }
    MF10(P0, 38) MF10(P1, 39)
#undef LDBH1
#undef MF10
}

__global__ __launch_bounds__(512, 2) void k_hihj(const float* __restrict__ roi, const float* __restrict__ b1,
                                                 const unsigned short* __restrict__ w1s,
                                                 unsigned short* __restrict__ Hi16,
                                                 unsigned short* __restrict__ Hjb16) {
    __shared__ __align__(16) char lds[81920];
    const int b = blockIdx.x >> 1, hh = blockIdx.x & 1, tid = threadIdx.x;
    const float* src = roi + (size_t)b * 64 * NH;
    const int wave = tid >> 6, lane = tid & 63, rlo = lane & 31, hsel = lane >> 5;
    const int colbase = wave * 160;
    const unsigned xr = (unsigned)(rlo & 7) << 4, h16 = (unsigned)hsel * 16u;
    const char* aA = lds + rlo * 1280;
    const char* bp = (const char*)(w1s + (size_t)hh * MAT_ELEMS) + (size_t)(colbase + rlo) * 32 + (size_t)hsel * 16;
    f32x16 acc[2][5];
#pragma unroll
    for (int rr = 0; rr < 2; ++rr)
#pragma unroll
        for (int c = 0; c < 5; ++c)
#pragma unroll
            for (int i = 0; i < 16; ++i) acc[rr][c][i] = 0.f;
    for (int kh = 0; kh < 2; ++kh) {
        if (kh) __syncthreads();
        for (int q = 0; q < 10; ++q) {
            int cid = tid + (q << 9);
            int row = cid / 80, c8 = (cid - row * 80) << 3, col = kh * 640 + c8;
            const float* r = src + row * NH + col;
            float4 v0 = *(const float4*)r, v1 = *(const float4*)(r + 4);
            uint4 pk;
            pk.x = pk2(v0.x, v0.y); pk.y = pk2(v0.z, v0.w);
            pk.z = pk2(v1.x, v1.y); pk.w = pk2(v1.z, v1.w);
            *(uint4*)(lds + row * 1280 + (((unsigned)(c8 << 1)) ^ ((unsigned)(row & 7) << 4))) = pk;
        }
        __syncthreads();
        gemm_half1(aA, xr, h16, bp + (size_t)kh * 40 * 40960, acc);
    }
    float bias[5];
#pragma unroll
    for (int cf = 0; cf < 5; ++cf) bias[cf] = hh ? b1[colbase + cf * 32 + rlo] : 0.f;
    unsigned short* dst = hh ? Hjb16 : Hi16;
#pragma unroll
    for (int rf = 0; rf < 2; ++rf)
#pragma unroll
        for (int cf = 0; cf < 5; ++cf) {
            int col = colbase + cf * 32 + rlo;
#pragma unroll
            for (int j = 0; j < 16; ++j) {
                int row = rf * 32 + (j & 3) + ((j >> 2) << 3) + (hsel << 2);
                dst[(size_t)(b * 64 + row) * NH + col] = bfb(acc[rf][cf][j] + bias[cf]);
            }
        }
}

// ---------------------------------------------------------------------------
// Shared per-kblk GEMM step: rf=4 (rows rw*128 + fr*32) x cf=2 per wave.
// ---------------------------------------------------------------------------
#define LDB1(D_, GKB_) { _Pragma("unroll") for (int cf = 0; cf < 2; ++cf) \
    D_[cf] = __builtin_bit_cast(bf16x8, *(const uint4*)(bp + (size_t)(GKB_) * 40960 + cf * 1024)); }

#define GSTEP(P_, KB_) { \
    unsigned ko = ((unsigned)((KB_) * 32 + hsel * 16)) ^ xr; \
    bf16x8 a0 = __builtin_bit_cast(bf16x8, *(const uint4*)(ap0 + ko)); \
    bf16x8 a1 = __builtin_bit_cast(bf16x8, *(const uint4*)(ap1 + ko)); \
    bf16x8 a2 = __builtin_bit_cast(bf16x8, *(const uint4*)(ap2 + ko)); \
    bf16x8 a3 = __builtin_bit_cast(bf16x8, *(const uint4*)(ap3 + ko)); \
    acc[0][0] = __builtin_amdgcn_mfma_f32_32x32x16_bf16(a0, P_[0], acc[0][0], 0, 0, 0); \
    acc[0][1] = __builtin_amdgcn_mfma_f32_32x32x16_bf16(a0, P_[1], acc[0][1], 0, 0, 0); \
    acc[1][0] = __builtin_amdgcn_mfma_f32_32x32x16_bf16(a1, P_[0], acc[1][0], 0, 0, 0); \
    acc[1][1] = __builtin_amdgcn_mfma_f32_32x32x16_bf16(a1, P_[1], acc[1][1], 0, 0, 0); \
    acc[2][0] = __builtin_amdgcn_mfma_f32_32x32x16_bf16(a2, P_[0], acc[2][0], 0, 0, 0); \
    acc[2][1] = __builtin_amdgcn_mfma_f32_32x32x16_bf16(a2, P_[1], acc[2][1], 0, 0, 0); \
    acc[3][0] = __builtin_amdgcn_mfma_f32_32x32x16_bf16(a3, P_[0], acc[3][0], 0, 0, 0); \
    acc[3][1] = __builtin_amdgcn_mfma_f32_32x32x16_bf16(a3, P_[1], acc[3][1], 0, 0, 0); \
    LDB1(P_, kc * 8 + (KB_) + 2) }

// ---------------------------------------------------------------------------
// k_g1: WG = (cb, b, ng): 256 rows (4 n x 64 m) x 256 cols of h2.
// A-tile (h1 chunk, 256x128 bf16 swizzled) built on the fly from bf16 Hi/Hjb.
// Epilogue: h2 -> two swizzled 64KB images (reusing A-dbuf LDS) -> ws.
// ---------------------------------------------------------------------------
__global__ __launch_bounds__(512, 2) void k_g1(const unsigned short* __restrict__ Hi16,
                                               const unsigned short* __restrict__ Hjb16,
                                               const float* __restrict__ b2,
                                               const unsigned short* __restrict__ w2s,
                                               char* __restrict__ h2g) {
    __shared__ __align__(16) char lds[131072];
    const int wg = blockIdx.x;
    const int cb = wg >> 8, r8 = wg & 255, b = r8 >> 4, ng = r8 & 15;
    const int tid = threadIdx.x;
    const int wave = tid >> 6, lane = tid & 63, rlo = lane & 31, hsel = lane >> 5;
    const int rw = wave >> 2, cw = wave & 3;
    const unsigned xr = ((unsigned)(rlo & 15)) << 4;

    const char* bp = (const char*)w2s + (size_t)(cb * 256 + cw * 64 + rlo) * 32 + (size_t)hsel * 16;
    const unsigned short* hisrc = Hi16 + (size_t)(b * 64) * NH;
    const unsigned short* hjsrc = Hjb16 + (size_t)(b * 64 + ng * 4) * NH;

    f32x16 acc[4][2];
#pragma unroll
    for (int fr = 0; fr < 4; ++fr)
#pragma unroll
        for (int c = 0; c < 2; ++c)
#pragma unroll
            for (int i = 0; i < 16; ++i) acc[fr][c][i] = 0.f;

    bf16x8 P0[2], P1[2];
    LDB1(P0, 0) LDB1(P1, 1)

#define G1LOAD(Q_, H_, J_, KN_) { int u_ = tid + ((Q_) << 9); int r_ = u_ >> 4, k_ = u_ & 15; \
    H_ = *(const uint4*)(hisrc + (size_t)(r_ & 63) * NH + (KN_) + k_ * 8); \
    J_ = *(const uint4*)(hjsrc + (size_t)(r_ >> 6) * NH + (KN_) + k_ * 8); }
#define G1WRITE(Q_, H_, J_, WB_) { int u_ = tid + ((Q_) << 9); int r_ = u_ >> 4, k_ = u_ & 15; \
    uint4 af_; af_.x = relu_add_pk(H_.x, J_.x); af_.y = relu_add_pk(H_.y, J_.y); \
    af_.z = relu_add_pk(H_.z, J_.z); af_.w = relu_add_pk(H_.w, J_.w); \
    *(uint4*)((WB_) + r_ * 256 + (((unsigned)(k_ * 16)) ^ (((unsigned)(r_ & 15)) << 4))) = af_; }

    // stage chunk 0
    {
        uint4 hu, ju;
#pragma unroll
        for (int q = 0; q < 8; ++q) { G1LOAD(q, hu, ju, 0) G1WRITE(q, hu, ju, lds) }
    }
    __syncthreads();

    for (int kc = 0; kc < 10; ++kc) {
        const char* ab = lds + ((kc & 1) << 16);
        char* wb = lds + (((kc & 1) ^ 1) << 16);
        const char* ap0 = ab + (rw * 128 +  0 + rlo) * 256;
        const char* ap1 = ab + (rw * 128 + 32 + rlo) * 256;
        const char* ap2 = ab + (rw * 128 + 64 + rlo) * 256;
        const char* ap3 = ab + (rw * 128 + 96 + rlo) * 256;
        const bool st = kc < 9;
        const int kn = (kc + 1) * 128;
        uint4 h0, h1, h2, h3, j0, j1, j2, j3;
        if (st) { G1LOAD(0, h0, j0, kn) G1LOAD(1, h1, j1, kn) G1LOAD(2, h2, j2, kn) G1LOAD(3, h3, j3, kn) }
        GSTEP(P0, 0) GSTEP(P1, 1) GSTEP(P0, 2) GSTEP(P1, 3)
        if (st) {
            G1WRITE(0, h0, j0, wb) G1WRITE(1, h1, j1, wb) G1WRITE(2, h2, j2, wb) G1WRITE(3, h3, j3, wb)
            G1LOAD(4, h0, j0, kn) G1LOAD(5, h1, j1, kn) G1LOAD(6, h2, j2, kn) G1LOAD(7, h3, j3, kn)
        }
        GSTEP(P0, 4) GSTEP(P1, 5) GSTEP(P0, 6) GSTEP(P1, 7)
        if (st) { G1WRITE(4, h0, j0, wb) G1WRITE(5, h1, j1, wb) G1WRITE(6, h2, j2, wb) G1WRITE(7, h3, j3, wb) }
        __syncthreads();
    }
#undef G1LOAD
#undef G1WRITE

    // epilogue: relu(acc+b2) -> bf16 swizzled images in LDS -> dump
    float bv[2];
    bv[0] = b2[cb * 256 + cw * 64 + rlo];
    bv[1] = b2[cb * 256 + cw * 64 + 32 + rlo];
#pragma unroll
    for (int fr = 0; fr < 4; ++fr)
#pragma unroll
        for (int cf = 0; cf < 2; ++cf)
#pragma unroll
            for (int j = 0; j < 16; ++j) {
                int r = rw * 128 + fr * 32 + (j & 3) + ((j >> 2) << 3) + (hsel << 2);
                int kk = cw * 64 + cf * 32 + rlo;
                unsigned off = ((unsigned)(kk >> 7) << 16) + (unsigned)r * 256u
                             + (((unsigned)((kk & 127) * 2)) ^ (((unsigned)(r & 15)) << 4));
                *(unsigned short*)(lds + off) = bfb(fmaxf(acc[fr][cf][j] + bv[cf], 0.f));
            }
    __syncthreads();
    {
        const u32x4* s = (const u32x4*)lds;
        u32x4* d = (u32x4*)(h2g + (size_t)((b * 16 + ng) * 10 + cb * 2) * 65536);
#pragma unroll
        for (int q = 0; q < 16; ++q) { int idx = tid + (q << 9); d[idx] = s[idx]; }
    }
}

// ---------------------------------------------------------------------------
// k_g2: WG = (b, ng, cb): rows = same 256, cols = W3 window. A = h2 images
// (raw 16B copies, pre-swizzled). Epilogue: relu+row-sum -> LDS psum -> atomic.
// ---------------------------------------------------------------------------
__global__ __launch_bounds__(512, 2) void k_g2(const char* __restrict__ h2g,
                                               const float* __restrict__ b3,
                                               const unsigned short* __restrict__ w3s,
                                               float* __restrict__ out) {
    __shared__ __align__(16) char lds[131072];
    const int wg = blockIdx.x;
    const int grp = wg / 5, cb = wg - grp * 5;
    const int b = grp >> 4, ng = grp & 15;
    const int tid = threadIdx.x;
    const int wave = tid >> 6, lane = tid & 63, rlo = lane & 31, hsel = lane >> 5;
    const int rw = wave >> 2, cw = wave & 3;
    const unsigned xr = ((unsigned)(rlo & 15)) << 4;

    const char* bp = (const char*)w3s + (size_t)(cb * 256 + cw * 64 + rlo) * 32 + (size_t)hsel * 16;
    const char* asrc = h2g + (size_t)(b * 16 + ng) * 10 * 65536;

    f32x16 acc[4][2];
#pragma unroll
    for (int fr = 0; fr < 4; ++fr)
#pragma unroll
        for (int c = 0; c < 2; ++c)
#pragma unroll
            for (int i = 0; i < 16; ++i) acc[fr][c][i] = 0.f;

    bf16x8 P0[2], P1[2];
    LDB1(P0, 0) LDB1(P1, 1)

    // stage chunk 0
#pragma unroll
    for (int q = 0; q < 8; ++q) {
        int idx = tid + (q << 9);
        *(u32x4*)(lds + (size_t)idx * 16) = *(const u32x4*)(asrc + (size_t)idx * 16);
    }
    __syncthreads();

    for (int kc = 0; kc < 10; ++kc) {
        const char* ab = lds + ((kc & 1) << 16);
        char* wb = lds + (((kc & 1) ^ 1) << 16);
        const char* ap0 = ab + (rw * 128 +  0 + rlo) * 256;
        const char* ap1 = ab + (rw * 128 + 32 + rlo) * 256;
        const char* ap2 = ab + (rw * 128 + 64 + rlo) * 256;
        const char* ap3 = ab + (rw * 128 + 96 + rlo) * 256;
        const bool st = kc < 9;
        const char* src = asrc + (size_t)(kc + 1) * 65536;
        u32x4 s0, s1, s2, s3;
        if (st) {
            s0 = *(const u32x4*)(src + tid * 16);
            s1 = *(const u32x4*)(src + tid * 16 + 8192);
            s2 = *(const u32x4*)(src + tid * 16 + 16384);
            s3 = *(const u32x4*)(src + tid * 16 + 24576);
        }
        GSTEP(P0, 0) GSTEP(P1, 1) GSTEP(P0, 2) GSTEP(P1, 3)
        if (st) {
            *(u32x4*)(wb + tid * 16) = s0;
            *(u32x4*)(wb + tid * 16 + 8192) = s1;
            *(u32x4*)(wb + tid * 16 + 16384) = s2;
            *(u32x4*)(wb + tid * 16 + 24576) = s3;
            s0 = *(const u32x4*)(src + tid * 16 + 32768);
            s1 = *(const u32x4*)(src + tid * 16 + 40960);
            s2 = *(const u32x4*)(src + tid * 16 + 49152);
            s3 = *(const u32x4*)(src + tid * 16 + 57344);
        }
        GSTEP(P0, 4) GSTEP(P1, 5) GSTEP(P0, 6) GSTEP(P1, 7)
        if (st) {
            *(u32x4*)(wb + tid * 16 + 32768) = s0;
            *(u32x4*)(wb + tid * 16 + 40960) = s1;
            *(u32x4*)(wb + tid * 16 + 49152) = s2;
            *(u32x4*)(wb + tid * 16 + 57344) = s3;
        }
        __syncthreads();
    }

    // epilogue: relu + row-sum
    float b3v[2];
    b3v[0] = b3[cb * 256 + cw * 64 + rlo];
    b3v[1] = b3[cb * 256 + cw * 64 + 32 + rlo];
    float cs[2];
#pragma unroll
    for (int cf = 0; cf < 2; ++cf) {
        float s = 0.f;
#pragma unroll
        for (int fr = 0; fr < 4; ++fr)
#pragma unroll
            for (int j = 0; j < 16; ++j) s += fmaxf(acc[fr][cf][j] + b3v[cf], 0.f);
        s += __shfl_xor(s, 32);
        cs[cf] = s;
    }
    float* psum = (float*)lds;   // [8 waves][64 cols]; Abuf dead after last barrier
    if (lane < 32) {
        psum[(wave << 6) + rlo] = cs[0];
        psum[(wave << 6) + 32 + rlo] = cs[1];
    }
    __syncthreads();
    if (tid < 256) {
        int cwi = tid >> 6, cr = tid & 63;
        float t = psum[(cwi << 6) + cr] + psum[((cwi + 4) << 6) + cr];
        atomicAdd(out + b * NH + cb * 256 + tid, t);
    }
}

extern "C" void kernel_launch(void* const* d_in, const int* in_sizes, int n_in,
                              void* d_out, int out_size, void* d_ws, size_t ws_size,
                              hipStream_t stream) {
    const float* roi = (const float*)d_in[0];
    const float* W1  = (const float*)d_in[1];
    const float* b1  = (const float*)d_in[2];
    const float* W2  = (const float*)d_in[3];
    const float* b2  = (const float*)d_in[4];
    const float* W3  = (const float*)d_in[5];
    const float* b3  = (const float*)d_in[6];
    float* out = (float*)d_out;
    char* ws = (char*)d_ws;
    unsigned short* w1s = (unsigned short*)(ws + OFF_W1S);
    unsigned short* w2s = (unsigned short*)(ws + OFF_W2S);
    unsigned short* w3s = (unsigned short*)(ws + OFF_W3S);
    unsigned short* Hi16  = (unsigned short*)(ws + OFF_HIB);
    unsigned short* Hjb16 = (unsigned short*)(ws + OFF_HJB);
    char* h2g = ws + OFF_H2;

    (void)hipMemsetAsync(out, 0, (size_t)16 * NH * sizeof(float), stream);

    k_cvt<<<dim3(80, 5), 256, 0, stream>>>(W1, w1s);
    k_cvt<<<dim3(80, 5), 256, 0, stream>>>(W1 + (size_t)NH * NH, w1s + MAT_ELEMS);
    k_cvt<<<dim3(80, 5), 256, 0, stream>>>(W2, w2s);
    k_cvt<<<dim3(80, 5), 256, 0, stream>>>(W3, w3s);

    k_hihj<<<32, 512, 0, stream>>>(roi, b1, w1s, Hi16, Hjb16);
    k_g1<<<1280, 512, 0, stream>>>(Hi16, Hjb16, b2, w2s, h2g);
    k_g2<<<1280, 512, 0, stream>>>(h2g, b3, w3s, out);
}